// Round 7
// baseline (143.537 us; speedup 1.0000x reference)
//
#include <hip/hip_runtime.h>
#include <math.h>

#define EPSF 1e-8f

// native clang vectors — accepted by __builtin_nontemporal_load/store
typedef float nvec4 __attribute__((ext_vector_type(4)));
typedef int   nivec4 __attribute__((ext_vector_type(4)));

__device__ __forceinline__ float pick(nvec4 v, int i) {
    return i == 0 ? v.x : i == 1 ? v.y : i == 2 ? v.z : v.w;
}

// Inclusive suffix scan of affine maps g(x)=A+Bx across the wave.
__device__ __forceinline__ void suffix_scan64(float& A, float& B, int lane) {
#pragma unroll
    for (int d = 1; d < 64; d <<= 1) {
        float Ao = __shfl_down(A, d);
        float Bo = __shfl_down(B, d);
        if (lane + d < 64) {
            A = fmaf(B, Ao, A);
            B = B * Bo;
        }
    }
}

// prep: gl[t] = γ·λ_t (t<S), gl[S] = γ; also emits sum_reward_weights.
__global__ __launch_bounds__(256)
void prep_kernel(const float* __restrict__ raw_gamma,
                 const float* __restrict__ raw_lambd, int lam_off,
                 float* __restrict__ gl, float* __restrict__ srw, int S)
{
    __shared__ float s_gl[1024];
    const float gamma = fmaxf(tanhf(raw_gamma[0]), EPSF);
    for (int t = threadIdx.x; t < S; t += 256) {
        float g1 = gamma * fmaxf(tanhf(raw_lambd[lam_off + t]), EPSF);
        gl[t] = g1;
        s_gl[t] = g1;
    }
    if (threadIdx.x == 0) gl[S] = gamma;
    __syncthreads();
    if (threadIdx.x >= 64) return;
    const int lane = threadIdx.x;
    const int base = lane << 4;           // 16 per lane over S=1024
    float a[16], b[16];
#pragma unroll
    for (int j = 0; j < 16; ++j) { b[j] = s_gl[base + j]; a[j] = gamma - b[j]; }
    float A = a[15], Bc = b[15];
#pragma unroll
    for (int j = 14; j >= 0; --j) { A = fmaf(b[j], A, a[j]); Bc *= b[j]; }
    suffix_scan64(A, Bc, lane);
    float EA = __shfl_down(A, 1);
    float EB = __shfl_down(Bc, 1);
    if (lane == 63) { EA = 0.0f; EB = 1.0f; }
    float v = EA + EB;                    // applied to v_next = 1.0
    float w[16], sum = 0.0f;
#pragma unroll
    for (int j = 15; j >= 0; --j) {
        v = fmaf(b[j], v, a[j]);
        w[j] = fmaxf(1.0f - v, EPSF);
        sum += w[j];
    }
#pragma unroll
    for (int d = 32; d; d >>= 1) sum += __shfl_xor(sum, d);
    float inv = 1.0f / fmaxf(sum / (float)S, EPSF);
#pragma unroll
    for (int j = 0; j < 16; ++j) srw[base + j] = w[j] * inv;
}

// One block per row; 4 waves = 4 chunks of 256; LDS stitch; NT streams.
// values loaded via an ALIGNED 16B cover (row base is only 4B-aligned):
// lane loads values[A0 + 4*lane .. +3] with A0 = E - sh, sh = E&3 uniform,
// then reconstructs v_{t+1..t+4} with 3 shuffles + uniform selects.
__global__ __launch_bounds__(256, 8)
void td_main(const float* __restrict__ gl,
             const float* __restrict__ values,
             const float* __restrict__ rewards,
             const int* __restrict__ dones,
             float* __restrict__ out, int B, int S)
{
    __shared__ float sA[4], sB[4];
    const int lane = threadIdx.x & 63;
    const int c    = threadIdx.x >> 6;    // chunk 0..3
    const int r    = blockIdx.x;
    const int C    = S >> 2;              // 256
    const int t0   = c * C + (lane << 2);

    const float4 G1  = *(const float4*)(gl + t0);
    const float gamma = gl[S];

    const size_t rb = (size_t)r * (S + 1);

    // Streams (all fully coalesced, nontemporal)
    nvec4  r4 = __builtin_nontemporal_load((const nvec4*)(rewards + (size_t)r * S + t0));
    nivec4 d4 = __builtin_nontemporal_load((const nivec4*)(dones + (size_t)r * S + t0));

    const int sh = (r + 1) & 3;           // (rb + c*C + 1) & 3 — block-uniform
    const size_t E  = rb + (size_t)c * C + 1;   // first needed v element
    const size_t A0 = E - sh;                   // 16B-aligned cover start
    nvec4 m4 = __builtin_nontemporal_load((const nvec4*)(values + A0) + lane);
    size_t A0t = A0 + 256;                      // tail (4 elems past cover)
    const size_t last4 = (size_t)B * (S + 1) - 4;
    if (A0t > last4) A0t = last4;               // stay in bounds (last row)
    nvec4 t4 = __builtin_nontemporal_load((const nvec4*)(values + A0t));
    const int delta = (int)(A0 + 256 - A0t);    // clamp shift (0 normally)
    float vS = values[rb + S];

    // Reconstruct v_{t+1}..v_{t+4} for this lane's 4 elements
    float n0 = __shfl_down(m4.x, 1);
    float n1 = __shfl_down(m4.y, 1);
    float n2 = __shfl_down(m4.z, 1);
    if (lane == 63) {
        n0 = pick(t4, delta);
        n1 = pick(t4, delta + 1 > 3 ? 3 : delta + 1);
        n2 = pick(t4, delta + 2 > 3 ? 3 : delta + 2);
    }
    float vn0, vn1, vn2, vn3;
    if (sh == 0)      { vn0 = m4.x; vn1 = m4.y; vn2 = m4.z; vn3 = m4.w; }
    else if (sh == 1) { vn0 = m4.y; vn1 = m4.z; vn2 = m4.w; vn3 = n0; }
    else if (sh == 2) { vn0 = m4.z; vn1 = m4.w; vn2 = n0;   vn3 = n1; }
    else              { vn0 = m4.w; vn1 = n0;   vn2 = n1;   vn3 = n2; }

    // Affine coefficients: ret_t = a_t + b_t * ret_{t+1}
    float vn[4] = {vn0, vn1, vn2, vn3};
    float rr[4] = {r4.x, r4.y, r4.z, r4.w};
    int   di[4] = {d4.x, d4.y, d4.z, d4.w};
    float g1v[4] = {G1.x, G1.y, G1.z, G1.w};
    float a[4], b[4];
#pragma unroll
    for (int j = 0; j < 4; ++j) {
        float ndn = 1.0f - (float)di[j];
        b[j] = g1v[j] * ndn;
        a[j] = fmaf((gamma - g1v[j]) * vn[j], ndn, rr[j]);
    }

    // Lane-local composite, then one 64-lane suffix scan
    float A = a[3], Bc = b[3];
#pragma unroll
    for (int j = 2; j >= 0; --j) { A = fmaf(b[j], A, a[j]); Bc *= b[j]; }
    suffix_scan64(A, Bc, lane);
    float EA = __shfl_down(A, 1);
    float EB = __shfl_down(Bc, 1);
    if (lane == 63) { EA = 0.0f; EB = 1.0f; }
    if (lane == 0) { sA[c] = A; sB[c] = Bc; }
    __syncthreads();

    // Carry into this chunk: apply later chunks' composites to v_S
    float x = vS;
#pragma unroll
    for (int j = 3; j >= 1; --j)
        if (j > c) x = fmaf(sB[j], x, sA[j]);   // block-uniform per wave

    float xi = fmaf(EB, x, EA);                 // ret at t0+4
    float o3 = fmaf(b[3], xi, a[3]);
    float o2 = fmaf(b[2], o3, a[2]);
    float o1 = fmaf(b[1], o2, a[1]);
    float o0 = fmaf(b[0], o1, a[0]);
    nvec4 ov = {o0, o1, o2, o3};
    __builtin_nontemporal_store(ov, (nvec4*)(out + (size_t)r * S + t0));
}

extern "C" void kernel_launch(void* const* d_in, const int* in_sizes, int n_in,
                              void* d_out, int out_size, void* d_ws, size_t ws_size,
                              hipStream_t stream) {
    const float* raw_gamma = (const float*)d_in[0];
    const float* raw_lambd = (const float*)d_in[1];
    const float* values    = (const float*)d_in[2];
    const float* rewards   = (const float*)d_in[3];
    const int*   dones     = (const int*)d_in[4];
    float* out = (float*)d_out;

    int n_v = in_sizes[2];           // B*(S+1)
    int n_r = in_sizes[3];           // B*S
    int B = n_v - n_r;               // 8192
    int S = n_r / B;                 // 1024
    int lam_off = in_sizes[1] - S;

    float* gl  = (float*)d_ws;               // S+1 floats (γλ table + γ)
    float* srw = out + (size_t)B * S;

    prep_kernel<<<1, 256, 0, stream>>>(raw_gamma, raw_lambd, lam_off, gl, srw, S);
    td_main<<<B, 256, 0, stream>>>(gl, values, rewards, dones, out, B, S);
}

// Round 8
// 138.051 us; speedup vs baseline: 1.0397x; 1.0397x over previous
//
#include <hip/hip_runtime.h>
#include <math.h>

#define EPSF 1e-8f

// native clang vectors — accepted by __builtin_nontemporal_load/store
typedef float nvec4 __attribute__((ext_vector_type(4)));
typedef int   nivec4 __attribute__((ext_vector_type(4)));

__device__ __forceinline__ float pick(nvec4 v, int i) {
    return i == 0 ? v.x : i == 1 ? v.y : i == 2 ? v.z : v.w;
}

// Inclusive suffix scan of affine maps g(x)=A+Bx across the wave.
__device__ __forceinline__ void suffix_scan64(float& A, float& B, int lane) {
#pragma unroll
    for (int d = 1; d < 64; d <<= 1) {
        float Ao = __shfl_down(A, d);
        float Bo = __shfl_down(B, d);
        if (lane + d < 64) {
            A = fmaf(B, Ao, A);
            B = B * Bo;
        }
    }
}

// Single fused kernel. Block r < B: one row, 4 waves = 4 chunks of 256,
// stitched through an 8-float LDS exchange + one barrier. No λ-table:
// each lane tanh's only its own 4 λ values. values stream goes through an
// ALIGNED 16B cover (row base ≡ r mod 4 elements) + shuffle reconstruct.
// Block r == B: sum_reward_weights on wave 0 (no LDS, no barrier).
__global__ __launch_bounds__(256, 8)
void td_kernel(const float* __restrict__ raw_gamma,
               const float* __restrict__ raw_lambd, int lam_off,
               const float* __restrict__ values,
               const float* __restrict__ rewards,
               const int* __restrict__ dones,
               float* __restrict__ out, int B, int S)
{
    __shared__ float sA[4], sB[4];
    const int lane = threadIdx.x & 63;
    const int c    = threadIdx.x >> 6;        // chunk 0..3
    const float gamma = fmaxf(tanhf(raw_gamma[0]), EPSF);

    if ((int)blockIdx.x == B) {
        // ---- sum_reward_weights: wave 0, self-contained ----
        if (threadIdx.x >= 64) return;
        const int base = lane << 4;           // 16 per lane over S=1024
        float a[16], b[16];
#pragma unroll
        for (int k = 0; k < 4; ++k) {
            float4 l4 = *(const float4*)(raw_lambd + lam_off + base + 4 * k);
            float lv[4] = {l4.x, l4.y, l4.z, l4.w};
#pragma unroll
            for (int j = 0; j < 4; ++j) {
                float g1 = gamma * fmaxf(tanhf(lv[j]), EPSF);
                b[4 * k + j] = g1;
                a[4 * k + j] = gamma - g1;
            }
        }
        float A = a[15], Bc = b[15];
#pragma unroll
        for (int j = 14; j >= 0; --j) { A = fmaf(b[j], A, a[j]); Bc *= b[j]; }
        suffix_scan64(A, Bc, lane);
        float EA = __shfl_down(A, 1);
        float EB = __shfl_down(Bc, 1);
        if (lane == 63) { EA = 0.0f; EB = 1.0f; }
        float v = EA + EB;                    // applied to v_next = 1.0
        float w[16], sum = 0.0f;
#pragma unroll
        for (int j = 15; j >= 0; --j) {
            v = fmaf(b[j], v, a[j]);
            w[j] = fmaxf(1.0f - v, EPSF);
            sum += w[j];
        }
#pragma unroll
        for (int d = 32; d; d >>= 1) sum += __shfl_xor(sum, d);
        float inv = 1.0f / fmaxf(sum / (float)S, EPSF);
        float* srw = out + (size_t)B * S;
#pragma unroll
        for (int j = 0; j < 16; ++j) srw[base + j] = w[j] * inv;
        return;
    }

    // ---- lambda_returns ----
    const int r  = blockIdx.x;
    const int C  = S >> 2;                    // 256
    const int t0 = c * C + (lane << 2);
    const size_t rb = (size_t)r * (S + 1);

    // Issue all stream loads up-front (coalesced, nontemporal).
    nvec4  r4 = __builtin_nontemporal_load((const nvec4*)(rewards + (size_t)r * S + t0));
    nivec4 d4 = __builtin_nontemporal_load((const nivec4*)(dones + (size_t)r * S + t0));

    const int sh = (r + 1) & 3;               // (rb + c*C + 1) & 3, block-uniform
    const size_t E  = rb + (size_t)c * C + 1; // first needed v element
    const size_t A0 = E - sh;                 // 16B-aligned cover start
    nvec4 m4 = __builtin_nontemporal_load((const nvec4*)(values + A0) + lane);
    size_t A0t = A0 + 256;                    // tail (4 elems past cover)
    const size_t last4 = (size_t)B * (S + 1) - 4;
    if (A0t > last4) A0t = last4;             // clamp (only hits on last row, sh=0)
    nvec4 t4 = __builtin_nontemporal_load((const nvec4*)(values + A0t));
    const int delta = (int)(A0 + 256 - A0t);
    float vS = values[rb + S];

    // λ coefficients: each lane tanh's only its 4 values (aligned float4).
    float4 l4 = *(const float4*)(raw_lambd + lam_off + t0);
    float lv[4] = {l4.x, l4.y, l4.z, l4.w};
    float g1v[4];
#pragma unroll
    for (int j = 0; j < 4; ++j)
        g1v[j] = gamma * fmaxf(tanhf(lv[j]), EPSF);

    // Reconstruct v_{t+1}..v_{t+4} from the aligned cover.
    float n0 = __shfl_down(m4.x, 1);
    float n1 = __shfl_down(m4.y, 1);
    float n2 = __shfl_down(m4.z, 1);
    if (lane == 63) {
        n0 = pick(t4, delta);
        n1 = pick(t4, delta + 1 > 3 ? 3 : delta + 1);
        n2 = pick(t4, delta + 2 > 3 ? 3 : delta + 2);
    }
    float vn0, vn1, vn2, vn3;
    if (sh == 0)      { vn0 = m4.x; vn1 = m4.y; vn2 = m4.z; vn3 = m4.w; }
    else if (sh == 1) { vn0 = m4.y; vn1 = m4.z; vn2 = m4.w; vn3 = n0; }
    else if (sh == 2) { vn0 = m4.z; vn1 = m4.w; vn2 = n0;   vn3 = n1; }
    else              { vn0 = m4.w; vn1 = n0;   vn2 = n1;   vn3 = n2; }

    // Affine coefficients: ret_t = a_t + b_t * ret_{t+1}
    float vn[4] = {vn0, vn1, vn2, vn3};
    float rr[4] = {r4.x, r4.y, r4.z, r4.w};
    int   di[4] = {d4.x, d4.y, d4.z, d4.w};
    float a[4], b[4];
#pragma unroll
    for (int j = 0; j < 4; ++j) {
        float ndn = 1.0f - (float)di[j];
        b[j] = g1v[j] * ndn;
        a[j] = fmaf((gamma - g1v[j]) * vn[j], ndn, rr[j]);
    }

    // Lane-local composite of 4 maps, then one 64-lane suffix scan.
    float A = a[3], Bc = b[3];
#pragma unroll
    for (int j = 2; j >= 0; --j) { A = fmaf(b[j], A, a[j]); Bc *= b[j]; }
    suffix_scan64(A, Bc, lane);
    float EA = __shfl_down(A, 1);
    float EB = __shfl_down(Bc, 1);
    if (lane == 63) { EA = 0.0f; EB = 1.0f; }
    if (lane == 0) { sA[c] = A; sB[c] = Bc; }
    __syncthreads();

    // Carry into this chunk: apply later chunks' composites to v_S.
    float x = vS;
#pragma unroll
    for (int j = 3; j >= 1; --j)
        if (j > c) x = fmaf(sB[j], x, sA[j]);   // block-uniform per wave

    float xi = fmaf(EB, x, EA);                 // ret at t0+4
    float o3 = fmaf(b[3], xi, a[3]);
    float o2 = fmaf(b[2], o3, a[2]);
    float o1 = fmaf(b[1], o2, a[1]);
    float o0 = fmaf(b[0], o1, a[0]);
    nvec4 ov = {o0, o1, o2, o3};
    __builtin_nontemporal_store(ov, (nvec4*)(out + (size_t)r * S + t0));
}

extern "C" void kernel_launch(void* const* d_in, const int* in_sizes, int n_in,
                              void* d_out, int out_size, void* d_ws, size_t ws_size,
                              hipStream_t stream) {
    const float* raw_gamma = (const float*)d_in[0];
    const float* raw_lambd = (const float*)d_in[1];
    const float* values    = (const float*)d_in[2];
    const float* rewards   = (const float*)d_in[3];
    const int*   dones     = (const int*)d_in[4];
    float* out = (float*)d_out;

    int n_v = in_sizes[2];           // B*(S+1)
    int n_r = in_sizes[3];           // B*S
    int B = n_v - n_r;               // 8192
    int S = n_r / B;                 // 1024
    int lam_off = in_sizes[1] - S;

    td_kernel<<<B + 1, 256, 0, stream>>>(
        raw_gamma, raw_lambd, lam_off, values, rewards, dones, out, B, S);
}